// Round 1
// baseline (471.182 us; speedup 1.0000x reference)
//
#include <hip/hip_runtime.h>

#define B_TOTAL 65536
#define TB 16
#define NTHR 256

struct MainParams {
  const float* xw;
  const int*   xcat;
  const float* xcont;
  const float* E0; const float* E1; const float* E2;
  const float* W1; const float* b1;
  const float* W2; const float* b2;
  const float* Wlin;
  const float* stats;   // scale[16], shift[16]
  float*       out;
  const float* wk[12];  // wk1a, wk1b, wk2a, wk2b, ..., wk6a, wk6b
};

// ---------------- BatchNorm stats: stage 1 (per-block partial sums) ----------
__global__ __launch_bounds__(256) void bn_partial(const float* __restrict__ xc,
                                                  float* __restrict__ ws) {
  __shared__ float red[512];
  const int t = threadIdx.x;
  const int c = t & 15, g = t >> 4;
  const int r0 = blockIdx.x * 256;
  float s = 0.f, q = 0.f;
  for (int i = 0; i < 16; ++i) {
    float v = xc[(size_t)(r0 + g + i * 16) * 16 + c];
    s += v; q += v * v;
  }
  red[t] = s; red[256 + t] = q;
  __syncthreads();
  if (t < 16) {
    float ss = 0.f, qq = 0.f;
    for (int gg = 0; gg < 16; ++gg) { ss += red[gg * 16 + t]; qq += red[256 + gg * 16 + t]; }
    ws[blockIdx.x * 32 + t] = ss;
    ws[blockIdx.x * 32 + 16 + t] = qq;
  }
}

// ---------------- BatchNorm stats: stage 2 (final scale/shift) ---------------
__global__ __launch_bounds__(256) void bn_final(const float* __restrict__ ws_in,
                                                float* __restrict__ ws_out,
                                                const float* __restrict__ g_,
                                                const float* __restrict__ b_) {
  __shared__ float red[512];
  const int t = threadIdx.x;
  const int c = t & 15, g = t >> 4;
  float s = 0.f, q = 0.f;
  for (int i = 0; i < 16; ++i) {
    int blk = g * 16 + i;
    s += ws_in[blk * 32 + c];
    q += ws_in[blk * 32 + 16 + c];
  }
  red[t] = s; red[256 + t] = q;
  __syncthreads();
  if (t < 16) {
    float ss = 0.f, qq = 0.f;
    for (int gg = 0; gg < 16; ++gg) { ss += red[gg * 16 + t]; qq += red[256 + gg * 16 + t]; }
    float mean  = ss / (float)B_TOTAL;
    float var   = qq / (float)B_TOTAL - mean * mean;
    float scale = g_[t] / sqrtf(var + 1e-5f);
    ws_out[8192 + t]      = scale;
    ws_out[8192 + 16 + t] = b_[t] - mean * scale;
  }
}

// ---------------- Fused main kernel: 16 samples per block --------------------
__global__ __launch_bounds__(256) void fused_main(MainParams p) {
  // LDS regions (62144 B total):
  __shared__ float s_ffc[TB][108];   // branch features (fa|fb interleaved per branch)
  __shared__ float s_x48[TB][48];    // emb(32) + bn(16)
  __shared__ float s_big[8736];      // reused: xw tile (16*240) -> h1 (16*520) -> Wlin (364*24)
  __shared__ float s_h2[TB][264];    // hidden2 (stride-padded)
  __shared__ float s_bn[32];
  __shared__ float s_wk[48];

  const int t  = threadIdx.x;
  const int s0 = blockIdx.x * TB;

  // --- Ph0: stage bn scale/shift + conv weights
  if (t < 32) s_bn[t] = p.stats[t];
  if (t < 12) {
    int br = t >> 1, ks = br + 1;
    int off = br * (br + 1) + (t & 1) * ks;
    const float* w = p.wk[t];
    for (int k = 0; k < ks; ++k) s_wk[off + k] = w[k];
  }
  __syncthreads();

  // --- Ph1: build x48 (emb + batchnorm) and stage xw tile into s_big
  for (int u = t; u < TB * 48; u += NTHR) {
    int s = u / 48, c = u - s * 48;
    int gs = s0 + s;
    float v;
    if (c < 20)      v = p.E0[(size_t)p.xcat[gs * 3 + 0] * 20 + c];
    else if (c < 24) v = p.E1[(size_t)p.xcat[gs * 3 + 1] * 4 + (c - 20)];
    else if (c < 32) v = p.E2[(size_t)p.xcat[gs * 3 + 2] * 8 + (c - 24)];
    else {
      int cc = c - 32;
      v = p.xcont[(size_t)gs * 16 + cc] * s_bn[cc] + s_bn[16 + cc];
    }
    s_x48[s][c] = v;
  }
  for (int u = t; u < TB * 60; u += NTHR) {
    int s = u / 60, m = u - s * 60;
    float4 v = *(const float4*)(p.xw + (size_t)(s0 + s) * 240 + 4 * m);
    *(float4*)&s_big[s * 240 + 4 * m] = v;
  }
  __syncthreads();

  // --- Ph2: fa = leaky(pool12(conv1(xw, wa, dil=1)))  -- rolling-window sums
  for (int u = t; u < TB * 72; u += NTHR) {
    int s = u / 72, rem = u - s * 72;
    int br = rem / 12, i = rem - br * 12;
    int ks = br + 1, lin = 240 - br;
    int si = (i * lin) / 12, ei = ((i + 1) * lin + 11) / 12;
    const float* row = &s_big[s * 240];
    float T = 0.f;
    for (int q = si; q < ei; ++q) T += row[q];
    const float* w = &s_wk[br * (br + 1)];
    float acc = w[0] * T;
    for (int k = 1; k < ks; ++k) {
      T += row[ei - 1 + k] - row[si + k - 1];
      acc += w[k] * T;
    }
    float m = acc / (float)(ei - si);
    s_ffc[s][br * 18 + i] = (m >= 0.f) ? m : 0.1f * m;
  }
  __syncthreads();

  // --- Ph3: fb = leaky(pool6(conv1(fa, wb, dil=2)))
  for (int u = t; u < TB * 36; u += NTHR) {
    int s = u / 36, rem = u - s * 36;
    int br = rem / 6, j = rem - br * 6;
    int ks = br + 1, lcb = 12 - 2 * br;
    int sj = (j * lcb) / 6, ej = ((j + 1) * lcb + 5) / 6;
    const float* fa = &s_ffc[s][br * 18];
    const float* w  = &s_wk[br * (br + 1) + ks];
    float acc = 0.f;
    for (int q = sj; q < ej; ++q) {
      float cv = 0.f;
      for (int k = 0; k < ks; ++k) cv += w[k] * fa[q + 2 * k];
      acc += cv;
    }
    float m = acc / (float)(ej - sj);
    s_ffc[s][br * 18 + 12 + j] = (m >= 0.f) ? m : 0.1f * m;
  }
  __syncthreads();

  // --- Ph4: GEMM1  h1[16][512] = relu(x48 @ W1 + b1), h1 -> s_big (stride 520)
  {
    float acc0[TB], acc1[TB];
    #pragma unroll
    for (int s = 0; s < TB; ++s) { acc0[s] = 0.f; acc1[s] = 0.f; }
    for (int k4 = 0; k4 < 48; k4 += 4) {
      float w0[4], w1[4];
      #pragma unroll
      for (int k = 0; k < 4; ++k) {
        w0[k] = p.W1[(size_t)(k4 + k) * 512 + t];
        w1[k] = p.W1[(size_t)(k4 + k) * 512 + t + 256];
      }
      #pragma unroll
      for (int s = 0; s < TB; ++s) {
        float4 xv = *(const float4*)&s_x48[s][k4];   // wave-uniform address: broadcast
        acc0[s] += xv.x * w0[0] + xv.y * w0[1] + xv.z * w0[2] + xv.w * w0[3];
        acc1[s] += xv.x * w1[0] + xv.y * w1[1] + xv.z * w1[2] + xv.w * w1[3];
      }
    }
    float bb0 = p.b1[t], bb1 = p.b1[t + 256];
    #pragma unroll
    for (int s = 0; s < TB; ++s) {
      float v0 = acc0[s] + bb0; v0 = v0 > 0.f ? v0 : 0.f;
      float v1 = acc1[s] + bb1; v1 = v1 > 0.f ? v1 : 0.f;
      s_big[s * 520 + t]       = v0;
      s_big[s * 520 + t + 256] = v1;
    }
  }
  __syncthreads();

  // --- Ph5: GEMM2  h2[16][256] = relu(h1 @ W2 + b2)
  // thread: 2 consecutive cols (j2, j2+1) x 8 samples
  {
    float a0[8], a1[8];
    #pragma unroll
    for (int si = 0; si < 8; ++si) { a0[si] = 0.f; a1[si] = 0.f; }
    const int j2    = (t & 127) * 2;
    const int sbase = (t >> 7) * 8;
    for (int k4 = 0; k4 < 512; k4 += 4) {
      float2 wv0 = *(const float2*)&p.W2[(size_t)(k4 + 0) * 256 + j2];
      float2 wv1 = *(const float2*)&p.W2[(size_t)(k4 + 1) * 256 + j2];
      float2 wv2 = *(const float2*)&p.W2[(size_t)(k4 + 2) * 256 + j2];
      float2 wv3 = *(const float2*)&p.W2[(size_t)(k4 + 3) * 256 + j2];
      #pragma unroll
      for (int si = 0; si < 8; ++si) {
        const float4 h = *(const float4*)&s_big[(sbase + si) * 520 + k4];  // broadcast
        a0[si] += h.x * wv0.x + h.y * wv1.x + h.z * wv2.x + h.w * wv3.x;
        a1[si] += h.x * wv0.y + h.y * wv1.y + h.z * wv2.y + h.w * wv3.y;
      }
    }
    float bb0 = p.b2[j2], bb1 = p.b2[j2 + 1];
    #pragma unroll
    for (int si = 0; si < 8; ++si) {
      float v0 = a0[si] + bb0; v0 = v0 > 0.f ? v0 : 0.f;
      float v1 = a1[si] + bb1; v1 = v1 > 0.f ? v1 : 0.f;
      *(float2*)&s_h2[sbase + si][j2] = make_float2(v0, v1);
    }
  }
  __syncthreads();

  // --- Ph6: stage Wlin into s_big (h1 dead), then out = [ffc, h2] @ Wlin
  for (int u = t; u < 364 * 24; u += NTHR) s_big[u] = p.Wlin[u];
  __syncthreads();
  for (int u = t; u < TB * 24; u += NTHR) {
    int s = u / 24, j = u - s * 24;
    float acc = 0.f;
    for (int k = 0; k < 108; ++k) acc += s_ffc[s][k] * s_big[k * 24 + j];
    for (int k = 0; k < 256; ++k) acc += s_h2[s][k] * s_big[(108 + k) * 24 + j];
    p.out[(size_t)(s0 + s) * 24 + j] = acc;
  }
}

extern "C" void kernel_launch(void* const* d_in, const int* in_sizes, int n_in,
                              void* d_out, int out_size, void* d_ws, size_t ws_size,
                              hipStream_t stream) {
  const float* xcont = (const float*)d_in[2];
  float* ws = (float*)d_ws;

  bn_partial<<<256, 256, 0, stream>>>(xcont, ws);
  bn_final<<<1, 256, 0, stream>>>(ws, ws, (const float*)d_in[18], (const float*)d_in[19]);

  MainParams p;
  p.xw    = (const float*)d_in[0];
  p.xcat  = (const int*)d_in[1];
  p.xcont = xcont;
  for (int i = 0; i < 12; ++i) p.wk[i] = (const float*)d_in[3 + i];
  p.E0 = (const float*)d_in[15]; p.E1 = (const float*)d_in[16]; p.E2 = (const float*)d_in[17];
  p.W1 = (const float*)d_in[20]; p.b1 = (const float*)d_in[21];
  p.W2 = (const float*)d_in[22]; p.b2 = (const float*)d_in[23];
  p.Wlin = (const float*)d_in[24];
  p.stats = ws + 8192;
  p.out = (float*)d_out;

  fused_main<<<B_TOTAL / TB, NTHR, 0, stream>>>(p);
}

// Round 2
// 140.084 us; speedup vs baseline: 3.3636x; 3.3636x over previous
//
#include <hip/hip_runtime.h>

typedef __bf16 bf16x8 __attribute__((ext_vector_type(8)));
typedef float  f32x4  __attribute__((ext_vector_type(4)));
typedef unsigned short ushort_t;

#define B_TOTAL 65536
#define TB 64
#define NTHR 512

// ---------------- helpers ----------------------------------------------------
__device__ __forceinline__ ushort_t f2bf(float f) {
  unsigned u = __builtin_bit_cast(unsigned, f);
  u += 0x7fffu + ((u >> 16) & 1u);          // RNE
  return (ushort_t)(u >> 16);
}
__device__ __forceinline__ float bf2f(ushort_t h) {
  return __builtin_bit_cast(float, (unsigned)h << 16);
}
// swizzled ushort index into a row-major bf16 LDS tile (rb = row stride bytes)
__device__ __forceinline__ int swzi(int row, int rb, int col) {
  return ((row * rb + col * 2) ^ ((row & 7) << 4)) >> 1;
}
__device__ __forceinline__ bf16x8 ld_frag(const ushort_t* p8) {
  return __builtin_bit_cast(bf16x8, *(const uint4*)p8);
}
__device__ __forceinline__ bf16x8 frag_swz(const ushort_t* base, int row, int rb, int kcol0) {
  int b = (row * rb + kcol0 * 2) ^ ((row & 7) << 4);
  return __builtin_bit_cast(bf16x8, *(const uint4*)((const char*)base + b));
}
__device__ __forceinline__ f32x4 mfma16(bf16x8 a, bf16x8 b, f32x4 c) {
  return __builtin_amdgcn_mfma_f32_16x16x32_bf16(a, b, c, 0, 0, 0);
}

// ---------------- BatchNorm stats --------------------------------------------
__global__ __launch_bounds__(256) void bn_partial(const float* __restrict__ xc,
                                                  float* __restrict__ ws) {
  __shared__ float red[512];
  const int t = threadIdx.x;
  const int c = t & 15, g = t >> 4;
  const int r0 = blockIdx.x * 256;
  float s = 0.f, q = 0.f;
  for (int i = 0; i < 16; ++i) {
    float v = xc[(size_t)(r0 + g + i * 16) * 16 + c];
    s += v; q += v * v;
  }
  red[t] = s; red[256 + t] = q;
  __syncthreads();
  if (t < 16) {
    float ss = 0.f, qq = 0.f;
    for (int gg = 0; gg < 16; ++gg) { ss += red[gg * 16 + t]; qq += red[256 + gg * 16 + t]; }
    ws[blockIdx.x * 32 + t] = ss;
    ws[blockIdx.x * 32 + 16 + t] = qq;
  }
}

__global__ __launch_bounds__(256) void bn_final(const float* __restrict__ ws_in,
                                                float* __restrict__ ws_out,
                                                const float* __restrict__ g_,
                                                const float* __restrict__ b_) {
  __shared__ float red[512];
  const int t = threadIdx.x;
  const int c = t & 15, g = t >> 4;
  float s = 0.f, q = 0.f;
  for (int i = 0; i < 16; ++i) {
    int blk = g * 16 + i;
    s += ws_in[blk * 32 + c];
    q += ws_in[blk * 32 + 16 + c];
  }
  red[t] = s; red[256 + t] = q;
  __syncthreads();
  if (t < 16) {
    float ss = 0.f, qq = 0.f;
    for (int gg = 0; gg < 16; ++gg) { ss += red[gg * 16 + t]; qq += red[256 + gg * 16 + t]; }
    float mean  = ss / (float)B_TOTAL;
    float var   = qq / (float)B_TOTAL - mean * mean;
    float scale = g_[t] / sqrtf(var + 1e-5f);
    ws_out[8192 + t]      = scale;
    ws_out[8192 + 16 + t] = b_[t] - mean * scale;
  }
}

// ---------------- Weight packing: f32 -> bf16 in MFMA B-fragment order -------
// layout: u = ((kb*NT + nt)*64 + lane)*8 + i ; value = W[kb*32 + (lane>>4)*8 + i][nt*16 + (lane&15)]
__global__ __launch_bounds__(256) void pack_weights(const float* __restrict__ W1,
                                                    const float* __restrict__ W2,
                                                    const float* __restrict__ Wl,
                                                    ushort_t* __restrict__ w1p,
                                                    ushort_t* __restrict__ w2p,
                                                    ushort_t* __restrict__ wlp) {
  int u = blockIdx.x * 256 + threadIdx.x;
  if (u < 32768) {                                 // W1: K 48->64, N 512 (NT=32, KB=2)
    int i = u & 7, lane = (u >> 3) & 63, kb = u >> 14;
    int k = kb * 32 + ((lane >> 4) << 3) + i;
    int n = (((u >> 9) & 31) << 4) + (lane & 15);
    w1p[u] = f2bf(k < 48 ? W1[k * 512 + n] : 0.f);
  } else if (u < 32768 + 131072) {                 // W2: K 512, N 256 (NT=16, KB=16)
    int v = u - 32768;
    int i = v & 7, lane = (v >> 3) & 63, kb = v >> 13;
    int k = kb * 32 + ((lane >> 4) << 3) + i;
    int n = (((v >> 9) & 15) << 4) + (lane & 15);
    w2p[v] = f2bf(W2[k * 256 + n]);
  } else if (u < 32768 + 131072 + 12288) {         // Wlin: K 364->384, N 24->32 (NT=2, KB=12)
    int v = u - (32768 + 131072);
    int i = v & 7, lane = (v >> 3) & 63, kb = v >> 10;
    int k = kb * 32 + ((lane >> 4) << 3) + i;
    int n = (((v >> 9) & 1) << 4) + (lane & 15);
    wlp[v] = f2bf((k < 364 && n < 24) ? Wl[k * 24 + n] : 0.f);
  }
}

// ---------------- Fused main: 64 samples / block, 8 waves --------------------
struct MainParams {
  const float* xw;
  const int*   xcat;
  const float* xcont;
  const float* E0; const float* E1; const float* E2;
  const float* b1; const float* b2;
  const ushort_t* w1p; const ushort_t* w2p; const ushort_t* wlp;
  const float* stats;
  float*       out;
  const float* wk[12];
};

__global__ __launch_bounds__(NTHR, 2) void fused_main(MainParams p) {
  // LDS carve (155968 B):
  //   [0,65536)       s_xw f32[64][240] (conv)  -> later s_h1 bf16[64][512] swz
  //   [65536,114688)  s_fc  bf16[64][384] swz  (ffc cols 0..107 | h2 cols 108..363 | pad)
  //   [114688,122880) s_x48 bf16[64][64]  swz
  //   [122880,155648) s_w2  bf16 double-buffered slab 2 x 16KB
  //   [155648,...)    s_bn f32[32], s_wk f32[48]
  __shared__ __align__(16) char smem[155968];
  float*    s_xw  = (float*)smem;
  ushort_t* s_h1  = (ushort_t*)smem;
  ushort_t* s_fc  = (ushort_t*)(smem + 65536);
  ushort_t* s_x48 = (ushort_t*)(smem + 114688);
  ushort_t* s_w2  = (ushort_t*)(smem + 122880);
  float*    s_bn  = (float*)(smem + 155648);
  float*    s_wk  = (float*)(smem + 155776);

  const int t    = threadIdx.x;
  const int lane = t & 63;
  const int w    = t >> 6;
  const int s0   = blockIdx.x * TB;
  const f32x4 fzero = {0.f, 0.f, 0.f, 0.f};

  // --- Ph0: stage bn scale/shift + conv weights; zero pad columns
  if (t < 32) s_bn[t] = p.stats[t];
  if (t >= 64 && t < 76) {
    int tt = t - 64, br = tt >> 1, ks = br + 1;
    int off = br * (br + 1) + (tt & 1) * ks;
    const float* wv = p.wk[tt];
    for (int k = 0; k < ks; ++k) s_wk[off + k] = wv[k];
  }
  for (int u = t; u < TB * 16; u += NTHR) { int s = u >> 4; s_x48[swzi(s, 128, 48 + (u & 15))] = 0; }
  for (int u = t; u < TB * 20; u += NTHR) { int s = u / 20; s_fc[swzi(s, 768, 364 + u % 20)] = 0; }
  __syncthreads();

  // --- Ph1: build x48 bf16 (emb + bn) and stage xw tile
  for (int u = t; u < TB * 48; u += NTHR) {
    int s = u / 48, c = u - s * 48, gs = s0 + s;
    float v;
    if (c < 20)      v = p.E0[(size_t)p.xcat[gs * 3 + 0] * 20 + c];
    else if (c < 24) v = p.E1[(size_t)p.xcat[gs * 3 + 1] * 4 + (c - 20)];
    else if (c < 32) v = p.E2[(size_t)p.xcat[gs * 3 + 2] * 8 + (c - 24)];
    else { int cc = c - 32; v = p.xcont[(size_t)gs * 16 + cc] * s_bn[cc] + s_bn[16 + cc]; }
    s_x48[swzi(s, 128, c)] = f2bf(v);
  }
  for (int u = t; u < TB * 60; u += NTHR) {
    int s = u / 60, m4 = u - s * 60;
    float4 v = *(const float4*)(p.xw + (size_t)(s0 + s) * 240 + 4 * m4);
    *(float4*)(s_xw + s * 240 + 4 * m4) = v;
  }
  __syncthreads();

  // --- Ph2a: in-place prefix sums per row (4 quarters of 60, then fixup)
  if (t < 256) {
    int s = t >> 2, q = t & 3;
    float* seg = s_xw + s * 240 + q * 60;
    float pp = 0.f;
    #pragma unroll
    for (int j = 0; j < 15; ++j) {
      float4 v = *(float4*)(seg + 4 * j);
      v.x += pp; v.y += v.x; v.z += v.y; v.w += v.z; pp = v.w;
      *(float4*)(seg + 4 * j) = v;
    }
  }
  __syncthreads();
  {
    int s = t / 3, q = (t % 3) + 1;
    float off = 0.f;
    if (t < 192) for (int pq = 0; pq < q; ++pq) off += s_xw[s * 240 + pq * 60 + 59];
    __syncthreads();
    if (t < 192) {
      float* seg = s_xw + s * 240 + q * 60;
      #pragma unroll
      for (int j = 0; j < 15; ++j) {
        float4 v = *(float4*)(seg + 4 * j);
        v.x += off; v.y += off; v.z += off; v.w += off;
        *(float4*)(seg + 4 * j) = v;
      }
    }
  }
  __syncthreads();

  // --- Ph2b: fa = leaky(pool12(conv1(xw, wa, 1))) via prefix sums
  for (int u = t; u < TB * 72; u += NTHR) {
    int s = u / 72, rem = u - s * 72;
    int br = rem / 12, i = rem - br * 12;
    int ks = br + 1, lin = 240 - br;
    int si = (i * lin) / 12, ei = ((i + 1) * lin + 11) / 12;
    const float* P  = s_xw + s * 240;   // P[x] stored at [x-1]; P[0]=0
    const float* wv = s_wk + br * (br + 1);
    float acc = 0.f;
    for (int k = 0; k < ks; ++k) {
      float pe = P[ei + k - 1];
      float ps = (si + k == 0) ? 0.f : P[si + k - 1];
      acc += wv[k] * (pe - ps);
    }
    float m = acc / (float)(ei - si);
    m = (m >= 0.f) ? m : 0.1f * m;
    s_fc[swzi(s, 768, br * 18 + i)] = f2bf(m);
  }
  __syncthreads();

  // --- Ph3: fb = leaky(pool6(conv1(fa, wb, 2)))
  for (int u = t; u < TB * 36; u += NTHR) {
    int s = u / 36, rem = u - s * 36;
    int br = rem / 6, j = rem - br * 6;
    int ks = br + 1, lcb = 12 - 2 * br;
    int sj = (j * lcb) / 6, ej = ((j + 1) * lcb + 5) / 6;
    const float* wv = s_wk + br * (br + 1) + ks;
    float acc = 0.f;
    for (int q = sj; q < ej; ++q)
      for (int k = 0; k < ks; ++k)
        acc += wv[k] * bf2f(s_fc[swzi(s, 768, br * 18 + q + 2 * k)]);
    float m = acc / (float)(ej - sj);
    m = (m >= 0.f) ? m : 0.1f * m;
    s_fc[swzi(s, 768, br * 18 + 12 + j)] = f2bf(m);
  }
  __syncthreads();

  // --- GEMM1: h1[64][512] = relu(x48 @ W1 + b1)   (wave = 2mt x 8nt, KB=2)
  {
    const int mh = w & 1, ng = w >> 1;
    bf16x8 a1f[2][2];
    #pragma unroll
    for (int jm = 0; jm < 2; ++jm)
      #pragma unroll
      for (int kb = 0; kb < 2; ++kb)
        a1f[jm][kb] = frag_swz(s_x48, (mh * 2 + jm) * 16 + (lane & 15), 128,
                               kb * 32 + ((lane >> 4) << 3));
    f32x4 acc1[2][8];
    #pragma unroll
    for (int jm = 0; jm < 2; ++jm)
      #pragma unroll
      for (int nl = 0; nl < 8; ++nl) acc1[jm][nl] = fzero;
    #pragma unroll
    for (int nl = 0; nl < 8; ++nl) {
      int nt = ng * 8 + nl;
      #pragma unroll
      for (int kb = 0; kb < 2; ++kb) {
        bf16x8 b = ld_frag(p.w1p + (size_t)((kb * 32 + nt) * 64 + lane) * 8);
        acc1[0][nl] = mfma16(a1f[0][kb], b, acc1[0][nl]);
        acc1[1][nl] = mfma16(a1f[1][kb], b, acc1[1][nl]);
      }
    }
    #pragma unroll
    for (int nl = 0; nl < 8; ++nl) {
      int n = (ng * 8 + nl) * 16 + (lane & 15);
      float bias = p.b1[n];
      #pragma unroll
      for (int jm = 0; jm < 2; ++jm) {
        int rowb = (mh * 2 + jm) * 16 + ((lane >> 4) << 2);
        #pragma unroll
        for (int r = 0; r < 4; ++r) {
          float v = acc1[jm][nl][r] + bias; v = v > 0.f ? v : 0.f;
          s_h1[swzi(rowb + r, 1024, n)] = f2bf(v);
        }
      }
    }
  }
  // preload W2 slab 0 into buffer 0 (each thread 2 x uint4 = whole 16KB slab)
  {
    const uint4* w2g = (const uint4*)p.w2p;
    uint4 a = w2g[2 * t], b = w2g[2 * t + 1];
    ((uint4*)s_w2)[2 * t] = a; ((uint4*)s_w2)[2 * t + 1] = b;
  }
  __syncthreads();

  // --- GEMM2: h2[64][256] = relu(h1 @ W2 + b2)   (wave = 2mt x 4nt, KB=16)
  {
    const int mh = w & 1, ng = w >> 1;
    const uint4* w2g = (const uint4*)p.w2p;
    f32x4 acc2[2][4];
    #pragma unroll
    for (int jm = 0; jm < 2; ++jm)
      #pragma unroll
      for (int jn = 0; jn < 4; ++jn) acc2[jm][jn] = fzero;

    for (int kb = 0; kb < 16; ++kb) {
      uint4 n0, n1;
      if (kb < 15) { n0 = w2g[(kb + 1) * 1024 + 2 * t]; n1 = w2g[(kb + 1) * 1024 + 2 * t + 1]; }
      const ushort_t* bbuf = s_w2 + (kb & 1) * 8192;
      bf16x8 a0 = frag_swz(s_h1, (mh * 2 + 0) * 16 + (lane & 15), 1024,
                           kb * 32 + ((lane >> 4) << 3));
      bf16x8 a1 = frag_swz(s_h1, (mh * 2 + 1) * 16 + (lane & 15), 1024,
                           kb * 32 + ((lane >> 4) << 3));
      #pragma unroll
      for (int jn = 0; jn < 4; ++jn) {
        bf16x8 b = ld_frag(bbuf + (size_t)((ng * 4 + jn) * 64 + lane) * 8);
        acc2[0][jn] = mfma16(a0, b, acc2[0][jn]);
        acc2[1][jn] = mfma16(a1, b, acc2[1][jn]);
      }
      if (kb < 15) {
        uint4* wbuf = (uint4*)(s_w2 + ((kb & 1) ^ 1) * 8192);
        wbuf[2 * t] = n0; wbuf[2 * t + 1] = n1;
      }
      __syncthreads();
    }
    // epilogue -> s_fc cols 108..363
    #pragma unroll
    for (int jn = 0; jn < 4; ++jn) {
      int n = (ng * 4 + jn) * 16 + (lane & 15);
      float bias = p.b2[n];
      #pragma unroll
      for (int jm = 0; jm < 2; ++jm) {
        int rowb = (mh * 2 + jm) * 16 + ((lane >> 4) << 2);
        #pragma unroll
        for (int r = 0; r < 4; ++r) {
          float v = acc2[jm][jn][r] + bias; v = v > 0.f ? v : 0.f;
          s_fc[swzi(rowb + r, 768, 108 + n)] = f2bf(v);
        }
      }
    }
  }
  __syncthreads();

  // --- GEMM3: out[64][24] = fc @ Wlin   (wave = 1mt x 1nt of 4x2, KB=12)
  {
    const int mt = w & 3, ntw = w >> 2;
    f32x4 acc3 = fzero;
    #pragma unroll
    for (int kb = 0; kb < 12; ++kb) {
      bf16x8 a = frag_swz(s_fc, mt * 16 + (lane & 15), 768, kb * 32 + ((lane >> 4) << 3));
      bf16x8 b = ld_frag(p.wlp + (size_t)((kb * 2 + ntw) * 64 + lane) * 8);
      acc3 = mfma16(a, b, acc3);
    }
    int col = ntw * 16 + (lane & 15);
    if (col < 24) {
      int rowb = s0 + mt * 16 + ((lane >> 4) << 2);
      #pragma unroll
      for (int r = 0; r < 4; ++r) p.out[(size_t)(rowb + r) * 24 + col] = acc3[r];
    }
  }
}

// ---------------- launch -----------------------------------------------------
extern "C" void kernel_launch(void* const* d_in, const int* in_sizes, int n_in,
                              void* d_out, int out_size, void* d_ws, size_t ws_size,
                              hipStream_t stream) {
  const float* xcont = (const float*)d_in[2];
  float* ws  = (float*)d_ws;
  char*  wsb = (char*)d_ws;
  ushort_t* w1p = (ushort_t*)(wsb + 36864);    //  64 KB
  ushort_t* w2p = (ushort_t*)(wsb + 102400);   // 256 KB
  ushort_t* wlp = (ushort_t*)(wsb + 364544);   //  24 KB (ws use ends at 389120 B)

  bn_partial<<<256, 256, 0, stream>>>(xcont, ws);
  bn_final<<<1, 256, 0, stream>>>(ws, ws, (const float*)d_in[18], (const float*)d_in[19]);
  pack_weights<<<688, 256, 0, stream>>>((const float*)d_in[20], (const float*)d_in[22],
                                        (const float*)d_in[24], w1p, w2p, wlp);

  MainParams p;
  p.xw    = (const float*)d_in[0];
  p.xcat  = (const int*)d_in[1];
  p.xcont = xcont;
  for (int i = 0; i < 12; ++i) p.wk[i] = (const float*)d_in[3 + i];
  p.E0 = (const float*)d_in[15]; p.E1 = (const float*)d_in[16]; p.E2 = (const float*)d_in[17];
  p.b1 = (const float*)d_in[21]; p.b2 = (const float*)d_in[23];
  p.w1p = w1p; p.w2p = w2p; p.wlp = wlp;
  p.stats = ws + 8192;
  p.out = (float*)d_out;

  fused_main<<<B_TOTAL / TB, NTHR, 0, stream>>>(p);
}

// Round 3
// 90.310 us; speedup vs baseline: 5.2174x; 1.5511x over previous
//
#include <hip/hip_runtime.h>

typedef __bf16 bf16x8 __attribute__((ext_vector_type(8)));
typedef float  f32x4  __attribute__((ext_vector_type(4)));
typedef unsigned short ushort_t;

#define B_TOTAL 65536
#define TB 32
#define NTHR 512

// ---------------- helpers ----------------------------------------------------
__device__ __forceinline__ ushort_t f2bf(float f) {
  unsigned u = __builtin_bit_cast(unsigned, f);
  u += 0x7fffu + ((u >> 16) & 1u);          // RNE
  return (ushort_t)(u >> 16);
}
__device__ __forceinline__ float bf2f(ushort_t h) {
  return __builtin_bit_cast(float, (unsigned)h << 16);
}
// packed bf16 pair (lo -> low 16 bits), HW RNE
__device__ __forceinline__ unsigned pk2(float lo, float hi) {
  unsigned r;
  asm("v_cvt_pk_bf16_f32 %0, %1, %2" : "=v"(r) : "v"(lo), "v"(hi));
  return r;
}
// swizzled ushort index into a row-major bf16 LDS tile (rb = row stride bytes)
__device__ __forceinline__ int swzi(int row, int rb, int col) {
  return ((row * rb + col * 2) ^ ((row & 7) << 4)) >> 1;
}
__device__ __forceinline__ bf16x8 ld_frag(const ushort_t* p8) {
  return __builtin_bit_cast(bf16x8, *(const uint4*)p8);
}
__device__ __forceinline__ bf16x8 frag_swz(const ushort_t* base, int row, int rb, int kcol0) {
  int b = (row * rb + kcol0 * 2) ^ ((row & 7) << 4);
  return __builtin_bit_cast(bf16x8, *(const uint4*)((const char*)base + b));
}
__device__ __forceinline__ f32x4 mfma16(bf16x8 a, bf16x8 b, f32x4 c) {
  return __builtin_amdgcn_mfma_f32_16x16x32_bf16(a, b, c, 0, 0, 0);
}

// ---------------- BatchNorm stats --------------------------------------------
__global__ __launch_bounds__(256) void bn_partial(const float* __restrict__ xc,
                                                  float* __restrict__ ws) {
  __shared__ float red[512];
  const int t = threadIdx.x;
  const int c = t & 15, g = t >> 4;
  const int r0 = blockIdx.x * 256;
  float s = 0.f, q = 0.f;
  for (int i = 0; i < 16; ++i) {
    float v = xc[(size_t)(r0 + g + i * 16) * 16 + c];
    s += v; q += v * v;
  }
  red[t] = s; red[256 + t] = q;
  __syncthreads();
  if (t < 16) {
    float ss = 0.f, qq = 0.f;
    for (int gg = 0; gg < 16; ++gg) { ss += red[gg * 16 + t]; qq += red[256 + gg * 16 + t]; }
    ws[blockIdx.x * 32 + t] = ss;
    ws[blockIdx.x * 32 + 16 + t] = qq;
  }
}

__global__ __launch_bounds__(256) void bn_final(const float* __restrict__ ws_in,
                                                float* __restrict__ ws_out,
                                                const float* __restrict__ g_,
                                                const float* __restrict__ b_) {
  __shared__ float red[512];
  const int t = threadIdx.x;
  const int c = t & 15, g = t >> 4;
  float s = 0.f, q = 0.f;
  for (int i = 0; i < 16; ++i) {
    int blk = g * 16 + i;
    s += ws_in[blk * 32 + c];
    q += ws_in[blk * 32 + 16 + c];
  }
  red[t] = s; red[256 + t] = q;
  __syncthreads();
  if (t < 16) {
    float ss = 0.f, qq = 0.f;
    for (int gg = 0; gg < 16; ++gg) { ss += red[gg * 16 + t]; qq += red[256 + gg * 16 + t]; }
    float mean  = ss / (float)B_TOTAL;
    float var   = qq / (float)B_TOTAL - mean * mean;
    float scale = g_[t] / sqrtf(var + 1e-5f);
    ws_out[8192 + t]      = scale;
    ws_out[8192 + 16 + t] = b_[t] - mean * scale;
  }
}

// ---------------- Weight packing: f32 -> bf16 in MFMA fragment order ---------
// u = ((kb*NT + nt)*64 + lane)*8 + i ; value = W[kb*32 + (lane>>4)*8 + i][nt*16 + (lane&15)]
__global__ __launch_bounds__(256) void pack_weights(const float* __restrict__ W1,
                                                    const float* __restrict__ W2,
                                                    const float* __restrict__ Wl,
                                                    ushort_t* __restrict__ w1p,
                                                    ushort_t* __restrict__ w2p,
                                                    ushort_t* __restrict__ wlp) {
  int u = blockIdx.x * 256 + threadIdx.x;
  if (u < 32768) {                                 // W1: K 48->64, N 512 (NT=32, KB=2)
    int i = u & 7, lane = (u >> 3) & 63, kb = u >> 14;
    int k = kb * 32 + ((lane >> 4) << 3) + i;
    int n = (((u >> 9) & 31) << 4) + (lane & 15);
    w1p[u] = f2bf(k < 48 ? W1[k * 512 + n] : 0.f);
  } else if (u < 32768 + 131072) {                 // W2: K 512, N 256 (NT=16, KB=16)
    int v = u - 32768;
    int i = v & 7, lane = (v >> 3) & 63, kb = v >> 13;
    int k = kb * 32 + ((lane >> 4) << 3) + i;
    int n = (((v >> 9) & 15) << 4) + (lane & 15);
    w2p[v] = f2bf(W2[k * 256 + n]);
  } else if (u < 32768 + 131072 + 12288) {         // Wlin: K 364->384, N 24->32 (NT=2, KB=12)
    int v = u - (32768 + 131072);
    int i = v & 7, lane = (v >> 3) & 63, kb = v >> 10;
    int k = kb * 32 + ((lane >> 4) << 3) + i;
    int n = (((v >> 9) & 1) << 4) + (lane & 15);
    wlp[v] = f2bf((k < 364 && n < 24) ? Wl[k * 24 + n] : 0.f);
  }
}

// ---------------- Fused main: 32 samples / block, 8 waves, 2 blocks/CU -------
struct MainParams {
  const float* xw;
  const int*   xcat;
  const float* xcont;
  const float* E0; const float* E1; const float* E2;
  const float* b1; const float* b2;
  const ushort_t* w1p; const ushort_t* w2p; const ushort_t* wlp;
  const float* stats;
  float*       out;
  const float* wk[12];
};

__global__ __launch_bounds__(NTHR, 4) void fused_main(MainParams p) {
  // LDS carve (61760 B -> 2 blocks/CU):
  //   [0,32768)       s_xw f32[32][240] (conv)  -> later s_h1 bf16[32][512] swz
  //   [32768,57344)   s_fc  bf16[32][384] swz  (ffc 0..107 | h2 108..363 | pad)
  //   [57344,61440)   s_x48 bf16[32][64]  swz
  //   [61440,61760)   s_bn f32[32], s_wk f32[48]
  __shared__ __align__(16) char smem[61760];
  float*    s_xw  = (float*)smem;
  ushort_t* s_h1  = (ushort_t*)smem;
  ushort_t* s_fc  = (ushort_t*)(smem + 32768);
  ushort_t* s_x48 = (ushort_t*)(smem + 57344);
  float*    s_bn  = (float*)(smem + 61440);
  float*    s_wk  = (float*)(smem + 61568);

  const int t    = threadIdx.x;
  const int lane = t & 63;
  const int w    = t >> 6;
  const int s0   = blockIdx.x * TB;
  const f32x4 fzero = {0.f, 0.f, 0.f, 0.f};

  // --- Ph0: stage bn scale/shift + conv weights; zero pad columns
  if (t < 32) s_bn[t] = p.stats[t];
  if (t >= 64 && t < 76) {
    int tt = t - 64, br = tt >> 1, ks = br + 1;
    int off = br * (br + 1) + (tt & 1) * ks;
    const float* wv = p.wk[tt];
    for (int k = 0; k < ks; ++k) s_wk[off + k] = wv[k];
  }
  for (int u = t; u < TB * 16; u += NTHR) { int s = u >> 4; s_x48[swzi(s, 128, 48 + (u & 15))] = 0; }
  for (int u = t; u < TB * 20; u += NTHR) { int s = u / 20; s_fc[swzi(s, 768, 364 + u % 20)] = 0; }
  __syncthreads();

  // --- Ph1: build x48 bf16 (emb + bn) and stage xw tile
  for (int u = t; u < TB * 48; u += NTHR) {
    int s = u / 48, c = u - s * 48, gs = s0 + s;
    float v;
    if (c < 20)      v = p.E0[(size_t)p.xcat[gs * 3 + 0] * 20 + c];
    else if (c < 24) v = p.E1[(size_t)p.xcat[gs * 3 + 1] * 4 + (c - 20)];
    else if (c < 32) v = p.E2[(size_t)p.xcat[gs * 3 + 2] * 8 + (c - 24)];
    else { int cc = c - 32; v = p.xcont[(size_t)gs * 16 + cc] * s_bn[cc] + s_bn[16 + cc]; }
    s_x48[swzi(s, 128, c)] = f2bf(v);
  }
  for (int u = t; u < TB * 60; u += NTHR) {
    int s = u / 60, m4 = u - s * 60;
    float4 v = *(const float4*)(p.xw + (size_t)(s0 + s) * 240 + 4 * m4);
    *(float4*)(s_xw + s * 240 + 4 * m4) = v;
  }
  __syncthreads();

  // --- Ph2a: in-place prefix sums per row (4 quarters of 60, then fixup)
  if (t < 4 * TB) {
    int s = t >> 2, q = t & 3;
    float* seg = s_xw + s * 240 + q * 60;
    float pp = 0.f;
    #pragma unroll
    for (int j = 0; j < 15; ++j) {
      float4 v = *(float4*)(seg + 4 * j);
      v.x += pp; v.y += v.x; v.z += v.y; v.w += v.z; pp = v.w;
      *(float4*)(seg + 4 * j) = v;
    }
  }
  __syncthreads();
  {
    int s = t / 3, q = (t % 3) + 1;
    float off = 0.f;
    if (t < 3 * TB) for (int pq = 0; pq < q; ++pq) off += s_xw[s * 240 + pq * 60 + 59];
    __syncthreads();
    if (t < 3 * TB) {
      float* seg = s_xw + s * 240 + q * 60;
      #pragma unroll
      for (int j = 0; j < 15; ++j) {
        float4 v = *(float4*)(seg + 4 * j);
        v.x += off; v.y += off; v.z += off; v.w += off;
        *(float4*)(seg + 4 * j) = v;
      }
    }
  }
  __syncthreads();

  // --- Ph2b: fa = leaky(pool12(conv1(xw, wa, 1))) via prefix sums
  for (int u = t; u < TB * 72; u += NTHR) {
    int s = u / 72, rem = u - s * 72;
    int br = rem / 12, i = rem - br * 12;
    int ks = br + 1, lin = 240 - br;
    int si = (i * lin) / 12, ei = ((i + 1) * lin + 11) / 12;
    const float* P  = s_xw + s * 240;   // P[x] stored at [x-1]; P[0]=0
    const float* wv = s_wk + br * (br + 1);
    float acc = 0.f;
    for (int k = 0; k < ks; ++k) {
      float pe = P[ei + k - 1];
      float ps = (si + k == 0) ? 0.f : P[si + k - 1];
      acc += wv[k] * (pe - ps);
    }
    float m = acc / (float)(ei - si);
    m = (m >= 0.f) ? m : 0.1f * m;
    s_fc[swzi(s, 768, br * 18 + i)] = f2bf(m);
  }
  __syncthreads();

  // --- Ph3: fb = leaky(pool6(conv1(fa, wb, 2)))   (shares interval with GEMM1)
  for (int u = t; u < TB * 36; u += NTHR) {
    int s = u / 36, rem = u - s * 36;
    int br = rem / 6, j = rem - br * 6;
    int ks = br + 1, lcb = 12 - 2 * br;
    int sj = (j * lcb) / 6, ej = ((j + 1) * lcb + 5) / 6;
    const float* wv = s_wk + br * (br + 1) + ks;
    float acc = 0.f;
    for (int q = sj; q < ej; ++q)
      for (int k = 0; k < ks; ++k)
        acc += wv[k] * bf2f(s_fc[swzi(s, 768, br * 18 + q + 2 * k)]);
    float m = acc / (float)(ej - sj);
    m = (m >= 0.f) ? m : 0.1f * m;
    s_fc[swzi(s, 768, br * 18 + 12 + j)] = f2bf(m);
  }

  // --- GEMM1: h1[32][512] = relu(x48 @ W1 + b1)
  // A = W1 frag (n-rows), B = x48 frag (sample-cols) -> D[n][sample]
  // wave w owns m-tiles {4w..4w+3} (n-dim), both sample-tiles, KB=2.
  {
    bf16x8 bx[2][2];
    #pragma unroll
    for (int st = 0; st < 2; ++st)
      #pragma unroll
      for (int kb = 0; kb < 2; ++kb)
        bx[st][kb] = frag_swz(s_x48, st * 16 + (lane & 15), 128, kb * 32 + ((lane >> 4) << 3));
    f32x4 acc[4][2];
    #pragma unroll
    for (int j = 0; j < 4; ++j) { acc[j][0] = fzero; acc[j][1] = fzero; }
    #pragma unroll
    for (int j = 0; j < 4; ++j) {
      int mt = w * 4 + j;
      #pragma unroll
      for (int kb = 0; kb < 2; ++kb) {
        bf16x8 a = ld_frag(p.w1p + (size_t)((kb * 32 + mt) * 64 + lane) * 8);
        acc[j][0] = mfma16(a, bx[0][kb], acc[j][0]);
        acc[j][1] = mfma16(a, bx[1][kb], acc[j][1]);
      }
    }
    #pragma unroll
    for (int j = 0; j < 4; ++j) {
      int n0 = (w * 4 + j) * 16 + ((lane >> 4) << 2);
      float4 bb = *(const float4*)(p.b1 + n0);
      #pragma unroll
      for (int st = 0; st < 2; ++st) {
        int srow = st * 16 + (lane & 15);
        float v0 = fmaxf(acc[j][st][0] + bb.x, 0.f);
        float v1 = fmaxf(acc[j][st][1] + bb.y, 0.f);
        float v2 = fmaxf(acc[j][st][2] + bb.z, 0.f);
        float v3 = fmaxf(acc[j][st][3] + bb.w, 0.f);
        uint2 pkv; pkv.x = pk2(v0, v1); pkv.y = pk2(v2, v3);
        *(uint2*)((char*)s_h1 + ((srow * 1024 + n0 * 2) ^ ((srow & 7) << 4))) = pkv;
      }
    }
  }
  __syncthreads();

  // --- GEMM2: h2[32][256] = relu(h1 @ W2 + b2)
  // wave w owns m-tiles {2w, 2w+1} (n-dim), both sample-tiles; KB=16, no barriers.
  {
    const int mt0 = w * 2;
    f32x4 acc[2][2];
    acc[0][0] = fzero; acc[0][1] = fzero; acc[1][0] = fzero; acc[1][1] = fzero;
    uint4 pa0 = *(const uint4*)(p.w2p + (size_t)((mt0 + 0) * 64 + lane) * 8);
    uint4 pa1 = *(const uint4*)(p.w2p + (size_t)((mt0 + 1) * 64 + lane) * 8);
    #pragma unroll
    for (int kb = 0; kb < 16; ++kb) {
      bf16x8 a0 = __builtin_bit_cast(bf16x8, pa0);
      bf16x8 a1 = __builtin_bit_cast(bf16x8, pa1);
      if (kb < 15) {
        pa0 = *(const uint4*)(p.w2p + (size_t)(((kb + 1) * 16 + mt0 + 0) * 64 + lane) * 8);
        pa1 = *(const uint4*)(p.w2p + (size_t)(((kb + 1) * 16 + mt0 + 1) * 64 + lane) * 8);
      }
      bf16x8 b0 = frag_swz(s_h1, (lane & 15),      1024, kb * 32 + ((lane >> 4) << 3));
      bf16x8 b1 = frag_swz(s_h1, 16 + (lane & 15), 1024, kb * 32 + ((lane >> 4) << 3));
      acc[0][0] = mfma16(a0, b0, acc[0][0]);
      acc[0][1] = mfma16(a0, b1, acc[0][1]);
      acc[1][0] = mfma16(a1, b0, acc[1][0]);
      acc[1][1] = mfma16(a1, b1, acc[1][1]);
    }
    #pragma unroll
    for (int jm = 0; jm < 2; ++jm) {
      int n0 = (mt0 + jm) * 16 + ((lane >> 4) << 2);
      float4 bb = *(const float4*)(p.b2 + n0);
      #pragma unroll
      for (int st = 0; st < 2; ++st) {
        int srow = st * 16 + (lane & 15);
        float v0 = fmaxf(acc[jm][st][0] + bb.x, 0.f);
        float v1 = fmaxf(acc[jm][st][1] + bb.y, 0.f);
        float v2 = fmaxf(acc[jm][st][2] + bb.z, 0.f);
        float v3 = fmaxf(acc[jm][st][3] + bb.w, 0.f);
        uint2 pkv; pkv.x = pk2(v0, v1); pkv.y = pk2(v2, v3);
        *(uint2*)((char*)s_fc + ((srow * 768 + (108 + n0) * 2) ^ ((srow & 7) << 4))) = pkv;
      }
    }
  }
  __syncthreads();

  // --- GEMM3: out[32][24] = fc @ Wlin   (waves 0-3; KB=12)
  if (w < 4) {
    const int mtile = w & 1, stile = w >> 1;
    f32x4 acc = fzero;
    #pragma unroll
    for (int kb = 0; kb < 12; ++kb) {
      bf16x8 a = ld_frag(p.wlp + (size_t)((kb * 2 + mtile) * 64 + lane) * 8);
      bf16x8 b = frag_swz(s_fc, stile * 16 + (lane & 15), 768, kb * 32 + ((lane >> 4) << 3));
      acc = mfma16(a, b, acc);
    }
    int n0 = mtile * 16 + ((lane >> 4) << 2);
    if (n0 < 24) {
      int sg = s0 + stile * 16 + (lane & 15);
      *(float2*)(p.out + (size_t)sg * 24 + n0)     = make_float2(acc[0], acc[1]);
      *(float2*)(p.out + (size_t)sg * 24 + n0 + 2) = make_float2(acc[2], acc[3]);
    }
  }
}

// ---------------- launch -----------------------------------------------------
extern "C" void kernel_launch(void* const* d_in, const int* in_sizes, int n_in,
                              void* d_out, int out_size, void* d_ws, size_t ws_size,
                              hipStream_t stream) {
  const float* xcont = (const float*)d_in[2];
  float* ws  = (float*)d_ws;
  char*  wsb = (char*)d_ws;
  ushort_t* w1p = (ushort_t*)(wsb + 36864);    //  64 KB
  ushort_t* w2p = (ushort_t*)(wsb + 102400);   // 256 KB
  ushort_t* wlp = (ushort_t*)(wsb + 364544);   //  24 KB (ws use ends at 389120 B)

  bn_partial<<<256, 256, 0, stream>>>(xcont, ws);
  bn_final<<<1, 256, 0, stream>>>(ws, ws, (const float*)d_in[18], (const float*)d_in[19]);
  pack_weights<<<688, 256, 0, stream>>>((const float*)d_in[20], (const float*)d_in[22],
                                        (const float*)d_in[24], w1p, w2p, wlp);

  MainParams p;
  p.xw    = (const float*)d_in[0];
  p.xcat  = (const int*)d_in[1];
  p.xcont = xcont;
  for (int i = 0; i < 12; ++i) p.wk[i] = (const float*)d_in[3 + i];
  p.E0 = (const float*)d_in[15]; p.E1 = (const float*)d_in[16]; p.E2 = (const float*)d_in[17];
  p.b1 = (const float*)d_in[21]; p.b2 = (const float*)d_in[23];
  p.w1p = w1p; p.w2p = w2p; p.wlp = wlp;
  p.stats = ws + 8192;
  p.out = (float*)d_out;

  fused_main<<<B_TOTAL / TB, NTHR, 0, stream>>>(p);
}

// Round 4
// 88.560 us; speedup vs baseline: 5.3205x; 1.0198x over previous
//
#include <hip/hip_runtime.h>

typedef __bf16 bf16x8 __attribute__((ext_vector_type(8)));
typedef float  f32x4  __attribute__((ext_vector_type(4)));
typedef unsigned short ushort_t;

#define B_TOTAL 65536
#define NSTILE  4096   // B_TOTAL / 16 sample-tiles

// ---------------- helpers ----------------------------------------------------
__device__ __forceinline__ ushort_t f2bf(float f) {
  unsigned u = __builtin_bit_cast(unsigned, f);
  u += 0x7fffu + ((u >> 16) & 1u);          // RNE
  return (ushort_t)(u >> 16);
}
__device__ __forceinline__ float bf2f(ushort_t h) {
  return __builtin_bit_cast(float, (unsigned)h << 16);
}
__device__ __forceinline__ unsigned pk2(float lo, float hi) {
  unsigned r;
  asm("v_cvt_pk_bf16_f32 %0, %1, %2" : "=v"(r) : "v"(lo), "v"(hi));
  return r;
}
// swizzled ushort index into a row-major bf16 LDS tile (rb = row stride bytes)
__device__ __forceinline__ int swzi(int row, int rb, int col) {
  return ((row * rb + col * 2) ^ ((row & 7) << 4)) >> 1;
}
__device__ __forceinline__ bf16x8 ld_frag(const ushort_t* p8) {
  return __builtin_bit_cast(bf16x8, *(const uint4*)p8);
}
__device__ __forceinline__ bf16x8 frag_swz(const ushort_t* base, int row, int rb, int kcol0) {
  int b = (row * rb + kcol0 * 2) ^ ((row & 7) << 4);
  return __builtin_bit_cast(bf16x8, *(const uint4*)((const char*)base + b));
}
__device__ __forceinline__ f32x4 mfma16(bf16x8 a, bf16x8 b, f32x4 c) {
  return __builtin_amdgcn_mfma_f32_16x16x32_bf16(a, b, c, 0, 0, 0);
}

// ---------------- BatchNorm stats --------------------------------------------
__global__ __launch_bounds__(256) void bn_partial(const float* __restrict__ xc,
                                                  float* __restrict__ ws) {
  __shared__ float red[512];
  const int t = threadIdx.x;
  const int c = t & 15, g = t >> 4;
  const int r0 = blockIdx.x * 256;
  float s = 0.f, q = 0.f;
  for (int i = 0; i < 16; ++i) {
    float v = xc[(size_t)(r0 + g + i * 16) * 16 + c];
    s += v; q += v * v;
  }
  red[t] = s; red[256 + t] = q;
  __syncthreads();
  if (t < 16) {
    float ss = 0.f, qq = 0.f;
    for (int gg = 0; gg < 16; ++gg) { ss += red[gg * 16 + t]; qq += red[256 + gg * 16 + t]; }
    ws[blockIdx.x * 32 + t] = ss;
    ws[blockIdx.x * 32 + 16 + t] = qq;
  }
}

__global__ __launch_bounds__(256) void bn_final(const float* __restrict__ ws_in,
                                                float* __restrict__ ws_out,
                                                const float* __restrict__ g_,
                                                const float* __restrict__ b_) {
  __shared__ float red[512];
  const int t = threadIdx.x;
  const int c = t & 15, g = t >> 4;
  float s = 0.f, q = 0.f;
  for (int i = 0; i < 16; ++i) {
    int blk = g * 16 + i;
    s += ws_in[blk * 32 + c];
    q += ws_in[blk * 32 + 16 + c];
  }
  red[t] = s; red[256 + t] = q;
  __syncthreads();
  if (t < 16) {
    float ss = 0.f, qq = 0.f;
    for (int gg = 0; gg < 16; ++gg) { ss += red[gg * 16 + t]; qq += red[256 + gg * 16 + t]; }
    float mean  = ss / (float)B_TOTAL;
    float var   = qq / (float)B_TOTAL - mean * mean;
    float scale = g_[t] / sqrtf(var + 1e-5f);
    ws_out[8192 + t]      = scale;
    ws_out[8192 + 16 + t] = b_[t] - mean * scale;
  }
}

// ---------------- Weight packing: f32 -> bf16 in MFMA fragment order ---------
// u = ((kb*NT + nt)*64 + lane)*8 + i ; value = W[kb*32 + (lane>>4)*8 + i][nt*16 + (lane&15)]
__global__ __launch_bounds__(256) void pack_weights(const float* __restrict__ W1,
                                                    const float* __restrict__ W2,
                                                    const float* __restrict__ Wl,
                                                    ushort_t* __restrict__ w1p,
                                                    ushort_t* __restrict__ w2p,
                                                    ushort_t* __restrict__ wlp) {
  int u = blockIdx.x * 256 + threadIdx.x;
  if (u < 32768) {                                 // W1: K 48->64, N 512 (NT=32, KB=2)
    int i = u & 7, lane = (u >> 3) & 63, kb = u >> 14;
    int k = kb * 32 + ((lane >> 4) << 3) + i;
    int n = (((u >> 9) & 31) << 4) + (lane & 15);
    w1p[u] = f2bf(k < 48 ? W1[k * 512 + n] : 0.f);
  } else if (u < 32768 + 131072) {                 // W2: K 512, N 256 (NT=16, KB=16)
    int v = u - 32768;
    int i = v & 7, lane = (v >> 3) & 63, kb = v >> 13;
    int k = kb * 32 + ((lane >> 4) << 3) + i;
    int n = (((v >> 9) & 15) << 4) + (lane & 15);
    w2p[v] = f2bf(W2[k * 256 + n]);
  } else if (u < 32768 + 131072 + 12288) {         // Wlin: K 384 (ffc 0..107 pad->128 | h2 128..383), N 24->32
    int v = u - (32768 + 131072);
    int i = v & 7, lane = (v >> 3) & 63, kb = v >> 10;
    int k = kb * 32 + ((lane >> 4) << 3) + i;
    int n = (((v >> 9) & 1) << 4) + (lane & 15);
    float val = 0.f;
    if (n < 24) {
      if (k < 108)       val = Wl[k * 24 + n];
      else if (k >= 128) val = Wl[(k - 20) * 24 + n];
    }
    wlp[v] = f2bf(val);
  }
}

// ---------------- Conv kernel: 32 samples / block, 4 waves, 4 blocks/CU ------
struct ConvParams {
  const float* xw;
  ushort_t*    ffc;        // packed B-frag order: ((kb*NSTILE + stile)*64 + lane)*8 + i
  const float* wk[12];
};

__global__ __launch_bounds__(256, 4) void conv_kernel(ConvParams p) {
  // LDS: 39104 B -> 4 blocks/CU
  __shared__ __align__(16) char smem[39104];
  float*    s_xw  = (float*)smem;              // [32][240] f32 (becomes prefix sums)
  ushort_t* s_ffc = (ushort_t*)(smem + 30720); // [32][128] bf16 swz rb=256
  float*    s_wk  = (float*)(smem + 38912);

  const int t  = threadIdx.x;
  const int s0 = blockIdx.x * 32;

  // stage conv weights + zero pad cols 108..127
  if (t < 12) {
    int br = t >> 1, ks = br + 1;
    int off = br * (br + 1) + (t & 1) * ks;
    const float* wv = p.wk[t];
    for (int k = 0; k < ks; ++k) s_wk[off + k] = wv[k];
  }
  for (int u = t; u < 32 * 20; u += 256) { int s = u / 20; s_ffc[swzi(s, 256, 108 + u % 20)] = 0; }
  for (int u = t; u < 32 * 60; u += 256) {
    int s = u / 60, m4 = u - s * 60;
    *(float4*)(s_xw + s * 240 + 4 * m4) = *(const float4*)(p.xw + (size_t)(s0 + s) * 240 + 4 * m4);
  }
  __syncthreads();

  // prefix sums per row: 4 quarters of 60
  if (t < 128) {
    int s = t >> 2, q = t & 3;
    float* seg = s_xw + s * 240 + q * 60;
    float pp = 0.f;
    #pragma unroll
    for (int j = 0; j < 15; ++j) {
      float4 v = *(float4*)(seg + 4 * j);
      v.x += pp; v.y += v.x; v.z += v.y; v.w += v.z; pp = v.w;
      *(float4*)(seg + 4 * j) = v;
    }
  }
  __syncthreads();
  {
    int s = t / 3, q = (t % 3) + 1;
    float off = 0.f;
    if (t < 96) for (int pq = 0; pq < q; ++pq) off += s_xw[s * 240 + pq * 60 + 59];
    __syncthreads();
    if (t < 96) {
      float* seg = s_xw + s * 240 + q * 60;
      #pragma unroll
      for (int j = 0; j < 15; ++j) {
        float4 v = *(float4*)(seg + 4 * j);
        v.x += off; v.y += off; v.z += off; v.w += off;
        *(float4*)(seg + 4 * j) = v;
      }
    }
  }
  __syncthreads();

  // fa = leaky(pool12(conv1(xw, wa, 1))) via prefix sums
  for (int u = t; u < 32 * 72; u += 256) {
    int s = u / 72, rem = u - s * 72;
    int br = rem / 12, i = rem - br * 12;
    int ks = br + 1, lin = 240 - br;
    int si = (i * lin) / 12, ei = ((i + 1) * lin + 11) / 12;
    const float* P  = s_xw + s * 240;   // P[x] stored at [x-1]; P[0]=0
    const float* wv = s_wk + br * (br + 1);
    float acc = 0.f;
    for (int k = 0; k < ks; ++k) {
      float pe = P[ei + k - 1];
      float ps = (si + k == 0) ? 0.f : P[si + k - 1];
      acc += wv[k] * (pe - ps);
    }
    float m = acc / (float)(ei - si);
    m = (m >= 0.f) ? m : 0.1f * m;
    s_ffc[swzi(s, 256, br * 18 + i)] = f2bf(m);
  }
  __syncthreads();

  // fb = leaky(pool6(conv1(fa, wb, 2)))
  for (int u = t; u < 32 * 36; u += 256) {
    int s = u / 36, rem = u - s * 36;
    int br = rem / 6, j = rem - br * 6;
    int ks = br + 1, lcb = 12 - 2 * br;
    int sj = (j * lcb) / 6, ej = ((j + 1) * lcb + 5) / 6;
    const float* wv = s_wk + br * (br + 1) + ks;
    float acc = 0.f;
    for (int q = sj; q < ej; ++q)
      for (int k = 0; k < ks; ++k)
        acc += wv[k] * bf2f(s_ffc[swzi(s, 256, br * 18 + q + 2 * k)]);
    float m = acc / (float)(ej - sj);
    m = (m >= 0.f) ? m : 0.1f * m;
    s_ffc[swzi(s, 256, br * 18 + 12 + j)] = f2bf(m);
  }
  __syncthreads();

  // packed write: element (kb, stile, lane, i) = ffc[stile*16 + (lane&15)][kb*32 + (lane>>4)*8 + i]
  for (int u = t; u < 512; u += 256) {
    int lane = u & 63, st = (u >> 6) & 1, kb = u >> 7;
    int row = st * 16 + (lane & 15);
    int colb = (kb * 32 + ((lane >> 4) << 3)) * 2;
    uint4 v = *(const uint4*)((const char*)s_ffc + ((row * 256 + colb) ^ ((row & 7) << 4)));
    size_t stile = (size_t)blockIdx.x * 2 + st;
    *(uint4*)((char*)p.ffc + (((size_t)kb * NSTILE + stile) * 64 + lane) * 16) = v;
  }
}

// ---------------- MLP kernel: 64 samples / block, 8 waves, 2 blocks/CU -------
struct MlpParams {
  const int*   xcat;
  const float* xcont;
  const float* E0; const float* E1; const float* E2;
  const float* b1; const float* b2;
  const ushort_t* w1p; const ushort_t* w2p; const ushort_t* wlp;
  const ushort_t* ffc;
  const float* stats;
  float*       out;
};

__global__ __launch_bounds__(512, 4) void mlp_kernel(MlpParams p) {
  // LDS: 73856 B -> 2 blocks/CU
  //   [0,65536)       s_h1 bf16[64][512] swz rb=1024 ; after GEMM2: s_fc bf16[64][256] swz rb=512
  //   [65536,73728)   s_x48 bf16[64][64] swz rb=128
  //   [73728,73856)   s_bn f32[32]
  __shared__ __align__(16) char smem[73856];
  ushort_t* s_h1  = (ushort_t*)smem;
  ushort_t* s_fc  = (ushort_t*)smem;
  ushort_t* s_x48 = (ushort_t*)(smem + 65536);
  float*    s_bn  = (float*)(smem + 73728);

  const int t    = threadIdx.x;
  const int lane = t & 63;
  const int w    = t >> 6;
  const int s0   = blockIdx.x * 64;
  const f32x4 fzero = {0.f, 0.f, 0.f, 0.f};

  if (t < 32) s_bn[t] = p.stats[t];
  for (int u = t; u < 64 * 16; u += 512) { int s = u >> 4; s_x48[swzi(s, 128, 48 + (u & 15))] = 0; }
  __syncthreads();

  // x48 = [emb | bn(xcont)]
  for (int u = t; u < 64 * 48; u += 512) {
    int s = u / 48, c = u - s * 48, gs = s0 + s;
    float v;
    if (c < 20)      v = p.E0[(size_t)p.xcat[gs * 3 + 0] * 20 + c];
    else if (c < 24) v = p.E1[(size_t)p.xcat[gs * 3 + 1] * 4 + (c - 20)];
    else if (c < 32) v = p.E2[(size_t)p.xcat[gs * 3 + 2] * 8 + (c - 24)];
    else { int cc = c - 32; v = p.xcont[(size_t)gs * 16 + cc] * s_bn[cc] + s_bn[16 + cc]; }
    s_x48[swzi(s, 128, c)] = f2bf(v);
  }
  __syncthreads();

  // --- GEMM1: h1[64 samp][512 n] = relu(x48 @ W1 + b1); D[n][sample]
  // wave w: nt = 4w..4w+3, st 0..3, kb 0..1
  {
    bf16x8 bx[4][2];
    #pragma unroll
    for (int st = 0; st < 4; ++st)
      #pragma unroll
      for (int kb = 0; kb < 2; ++kb)
        bx[st][kb] = frag_swz(s_x48, st * 16 + (lane & 15), 128, kb * 32 + ((lane >> 4) << 3));
    #pragma unroll
    for (int j = 0; j < 4; ++j) {
      int nt = w * 4 + j;
      bf16x8 a0 = ld_frag(p.w1p + (size_t)((0 * 32 + nt) * 64 + lane) * 8);
      bf16x8 a1 = ld_frag(p.w1p + (size_t)((1 * 32 + nt) * 64 + lane) * 8);
      f32x4 acc[4];
      #pragma unroll
      for (int st = 0; st < 4; ++st) {
        acc[st] = mfma16(a0, bx[st][0], fzero);
        acc[st] = mfma16(a1, bx[st][1], acc[st]);
      }
      int n0 = nt * 16 + ((lane >> 4) << 2);
      float4 bb = *(const float4*)(p.b1 + n0);
      #pragma unroll
      for (int st = 0; st < 4; ++st) {
        int row = st * 16 + (lane & 15);
        float v0 = fmaxf(acc[st][0] + bb.x, 0.f);
        float v1 = fmaxf(acc[st][1] + bb.y, 0.f);
        float v2 = fmaxf(acc[st][2] + bb.z, 0.f);
        float v3 = fmaxf(acc[st][3] + bb.w, 0.f);
        uint2 pkv; pkv.x = pk2(v0, v1); pkv.y = pk2(v2, v3);
        *(uint2*)((char*)s_h1 + ((row * 1024 + n0 * 2) ^ ((row & 7) << 4))) = pkv;
      }
    }
  }
  __syncthreads();

  // --- GEMM2: h2[64][256] = relu(h1 @ W2 + b2); wave w: nt = 2w, 2w+1; KB=16, no K-loop barriers
  {
    const int nt0 = w * 2;
    f32x4 acc[2][4];
    #pragma unroll
    for (int jm = 0; jm < 2; ++jm)
      #pragma unroll
      for (int st = 0; st < 4; ++st) acc[jm][st] = fzero;
    uint4 pa[2][2];
    pa[0][0] = *(const uint4*)(p.w2p + (size_t)((0 * 16 + nt0 + 0) * 64 + lane) * 8);
    pa[0][1] = *(const uint4*)(p.w2p + (size_t)((0 * 16 + nt0 + 1) * 64 + lane) * 8);
    pa[1][0] = *(const uint4*)(p.w2p + (size_t)((1 * 16 + nt0 + 0) * 64 + lane) * 8);
    pa[1][1] = *(const uint4*)(p.w2p + (size_t)((1 * 16 + nt0 + 1) * 64 + lane) * 8);
    #pragma unroll
    for (int kb = 0; kb < 16; ++kb) {
      bf16x8 a0 = __builtin_bit_cast(bf16x8, pa[kb & 1][0]);
      bf16x8 a1 = __builtin_bit_cast(bf16x8, pa[kb & 1][1]);
      if (kb < 14) {
        pa[kb & 1][0] = *(const uint4*)(p.w2p + (size_t)(((kb + 2) * 16 + nt0 + 0) * 64 + lane) * 8);
        pa[kb & 1][1] = *(const uint4*)(p.w2p + (size_t)(((kb + 2) * 16 + nt0 + 1) * 64 + lane) * 8);
      }
      #pragma unroll
      for (int st = 0; st < 4; ++st) {
        bf16x8 b = frag_swz(s_h1, st * 16 + (lane & 15), 1024, kb * 32 + ((lane >> 4) << 3));
        acc[0][st] = mfma16(a0, b, acc[0][st]);
        acc[1][st] = mfma16(a1, b, acc[1][st]);
      }
    }
    __syncthreads();   // all h1 reads complete before overlaying region with h2
    #pragma unroll
    for (int jm = 0; jm < 2; ++jm) {
      int n0 = (nt0 + jm) * 16 + ((lane >> 4) << 2);
      float4 bb = *(const float4*)(p.b2 + n0);
      #pragma unroll
      for (int st = 0; st < 4; ++st) {
        int row = st * 16 + (lane & 15);
        float v0 = fmaxf(acc[jm][st][0] + bb.x, 0.f);
        float v1 = fmaxf(acc[jm][st][1] + bb.y, 0.f);
        float v2 = fmaxf(acc[jm][st][2] + bb.z, 0.f);
        float v3 = fmaxf(acc[jm][st][3] + bb.w, 0.f);
        uint2 pkv; pkv.x = pk2(v0, v1); pkv.y = pk2(v2, v3);
        *(uint2*)((char*)s_fc + ((row * 512 + n0 * 2) ^ ((row & 7) << 4))) = pkv;
      }
    }
  }
  __syncthreads();

  // --- GEMM3: out[64][24] = [ffc(pad128) | h2] @ Wlin ; wave w: st = w&3, nt = w>>2
  {
    const int st = w & 3, nt = w >> 2;
    const size_t stile = (size_t)blockIdx.x * 4 + st;
    f32x4 acc = fzero;
    #pragma unroll
    for (int kb = 0; kb < 12; ++kb) {
      bf16x8 a = ld_frag(p.wlp + (size_t)((kb * 2 + nt) * 64 + lane) * 8);
      bf16x8 b;
      if (kb < 4) b = ld_frag(p.ffc + (((size_t)kb * NSTILE + stile) * 64 + lane) * 8);
      else        b = frag_swz(s_fc, st * 16 + (lane & 15), 512, (kb - 4) * 32 + ((lane >> 4) << 3));
      acc = mfma16(a, b, acc);
    }
    int n0 = nt * 16 + ((lane >> 4) << 2);
    if (n0 < 24) {
      int sg = s0 + st * 16 + (lane & 15);
      *(float2*)(p.out + (size_t)sg * 24 + n0)     = make_float2(acc[0], acc[1]);
      *(float2*)(p.out + (size_t)sg * 24 + n0 + 2) = make_float2(acc[2], acc[3]);
    }
  }
}

// ---------------- launch -----------------------------------------------------
extern "C" void kernel_launch(void* const* d_in, const int* in_sizes, int n_in,
                              void* d_out, int out_size, void* d_ws, size_t ws_size,
                              hipStream_t stream) {
  const float* xcont = (const float*)d_in[2];
  float* ws  = (float*)d_ws;
  char*  wsb = (char*)d_ws;
  ushort_t* w1p = (ushort_t*)(wsb + 36864);    //  64 KB
  ushort_t* w2p = (ushort_t*)(wsb + 102400);   // 256 KB
  ushort_t* wlp = (ushort_t*)(wsb + 364544);   //  24 KB
  ushort_t* ffc = (ushort_t*)(wsb + 524288);   //  16.78 MB (4kb x 4096 stiles x 1KB)

  ConvParams cp;
  cp.xw = (const float*)d_in[0];
  cp.ffc = ffc;
  for (int i = 0; i < 12; ++i) cp.wk[i] = (const float*)d_in[3 + i];
  conv_kernel<<<B_TOTAL / 32, 256, 0, stream>>>(cp);

  bn_partial<<<256, 256, 0, stream>>>(xcont, ws);
  bn_final<<<1, 256, 0, stream>>>(ws, ws, (const float*)d_in[18], (const float*)d_in[19]);
  pack_weights<<<688, 256, 0, stream>>>((const float*)d_in[20], (const float*)d_in[22],
                                        (const float*)d_in[24], w1p, w2p, wlp);

  MlpParams p;
  p.xcat  = (const int*)d_in[1];
  p.xcont = xcont;
  p.E0 = (const float*)d_in[15]; p.E1 = (const float*)d_in[16]; p.E2 = (const float*)d_in[17];
  p.b1 = (const float*)d_in[21]; p.b2 = (const float*)d_in[23];
  p.w1p = w1p; p.w2p = w2p; p.wlp = wlp; p.ffc = ffc;
  p.stats = ws + 8192;
  p.out = (float*)d_out;
  mlp_kernel<<<B_TOTAL / 64, 512, 0, stream>>>(p);
}

// Round 5
// 69.659 us; speedup vs baseline: 6.7641x; 1.2713x over previous
//
#include <hip/hip_runtime.h>

typedef __bf16 bf16x8 __attribute__((ext_vector_type(8)));
typedef float  f32x4  __attribute__((ext_vector_type(4)));
typedef unsigned short ushort_t;

#define B_TOTAL 65536
#define NSTILE  4096   // B_TOTAL / 16 sample-tiles

// ---------------- helpers ----------------------------------------------------
__device__ __forceinline__ ushort_t f2bf(float f) {
  unsigned u = __builtin_bit_cast(unsigned, f);
  u += 0x7fffu + ((u >> 16) & 1u);          // RNE
  return (ushort_t)(u >> 16);
}
__device__ __forceinline__ unsigned pk2(float lo, float hi) {
  unsigned r;
  asm("v_cvt_pk_bf16_f32 %0, %1, %2" : "=v"(r) : "v"(lo), "v"(hi));
  return r;
}
__device__ __forceinline__ float lrelu(float v) { return v >= 0.f ? v : 0.1f * v; }
// swizzled ushort index into a row-major bf16 LDS tile (rb = row stride bytes, mult of 128)
__device__ __forceinline__ int swzi(int row, int rb, int col) {
  return ((row * rb + col * 2) ^ ((row & 7) << 4)) >> 1;
}
__device__ __forceinline__ bf16x8 ld_frag(const ushort_t* p8) {
  return __builtin_bit_cast(bf16x8, *(const uint4*)p8);
}
__device__ __forceinline__ bf16x8 frag_swz(const ushort_t* base, int row, int rb, int kcol0) {
  int b = (row * rb + kcol0 * 2) ^ ((row & 7) << 4);
  return __builtin_bit_cast(bf16x8, *(const uint4*)((const char*)base + b));
}
__device__ __forceinline__ f32x4 mfma16(bf16x8 a, bf16x8 b, f32x4 c) {
  return __builtin_amdgcn_mfma_f32_16x16x32_bf16(a, b, c, 0, 0, 0);
}

// ---------------- BatchNorm stats --------------------------------------------
__global__ __launch_bounds__(256) void bn_partial(const float* __restrict__ xc,
                                                  float* __restrict__ ws) {
  __shared__ float red[512];
  const int t = threadIdx.x;
  const int c = t & 15, g = t >> 4;
  const int r0 = blockIdx.x * 256;
  float s = 0.f, q = 0.f;
  for (int i = 0; i < 16; ++i) {
    float v = xc[(size_t)(r0 + g + i * 16) * 16 + c];
    s += v; q += v * v;
  }
  red[t] = s; red[256 + t] = q;
  __syncthreads();
  if (t < 16) {
    float ss = 0.f, qq = 0.f;
    for (int gg = 0; gg < 16; ++gg) { ss += red[gg * 16 + t]; qq += red[256 + gg * 16 + t]; }
    ws[blockIdx.x * 32 + t] = ss;
    ws[blockIdx.x * 32 + 16 + t] = qq;
  }
}

__global__ __launch_bounds__(256) void bn_final(const float* __restrict__ ws_in,
                                                float* __restrict__ ws_out,
                                                const float* __restrict__ g_,
                                                const float* __restrict__ b_) {
  __shared__ float red[512];
  const int t = threadIdx.x;
  const int c = t & 15, g = t >> 4;
  float s = 0.f, q = 0.f;
  for (int i = 0; i < 16; ++i) {
    int blk = g * 16 + i;
    s += ws_in[blk * 32 + c];
    q += ws_in[blk * 32 + 16 + c];
  }
  red[t] = s; red[256 + t] = q;
  __syncthreads();
  if (t < 16) {
    float ss = 0.f, qq = 0.f;
    for (int gg = 0; gg < 16; ++gg) { ss += red[gg * 16 + t]; qq += red[256 + gg * 16 + t]; }
    float mean  = ss / (float)B_TOTAL;
    float var   = qq / (float)B_TOTAL - mean * mean;
    float scale = g_[t] / sqrtf(var + 1e-5f);
    ws_out[8192 + t]      = scale;
    ws_out[8192 + 16 + t] = b_[t] - mean * scale;
  }
}

// ---------------- Weight packing: f32 -> bf16 in MFMA fragment order ---------
__global__ __launch_bounds__(256) void pack_weights(const float* __restrict__ W1,
                                                    const float* __restrict__ W2,
                                                    const float* __restrict__ Wl,
                                                    ushort_t* __restrict__ w1p,
                                                    ushort_t* __restrict__ w2p,
                                                    ushort_t* __restrict__ wlp) {
  int u = blockIdx.x * 256 + threadIdx.x;
  if (u < 32768) {                                 // W1: K 48->64, N 512 (NT=32, KB=2)
    int i = u & 7, lane = (u >> 3) & 63, kb = u >> 14;
    int k = kb * 32 + ((lane >> 4) << 3) + i;
    int n = (((u >> 9) & 31) << 4) + (lane & 15);
    w1p[u] = f2bf(k < 48 ? W1[k * 512 + n] : 0.f);
  } else if (u < 32768 + 131072) {                 // W2: K 512, N 256 (NT=16, KB=16)
    int v = u - 32768;
    int i = v & 7, lane = (v >> 3) & 63, kb = v >> 13;
    int k = kb * 32 + ((lane >> 4) << 3) + i;
    int n = (((v >> 9) & 15) << 4) + (lane & 15);
    w2p[v] = f2bf(W2[k * 256 + n]);
  } else if (u < 32768 + 131072 + 12288) {         // Wlin: K 384 (ffc 0..107 pad->128 | h2 128..383), N 24->32
    int v = u - (32768 + 131072);
    int i = v & 7, lane = (v >> 3) & 63, kb = v >> 10;
    int k = kb * 32 + ((lane >> 4) << 3) + i;
    int n = (((v >> 9) & 1) << 4) + (lane & 15);
    float val = 0.f;
    if (n < 24) {
      if (k < 108)       val = Wl[k * 24 + n];
      else if (k >= 128) val = Wl[(k - 20) * 24 + n];
    }
    wlp[v] = f2bf(val);
  }
}

// ---------------- Conv-as-GEMM weight matrices -------------------------------
// Apack: [8 kb][5 nt][64 lane][8] — A[k (xw pos 0..239)][n (fa idx br*12+i)]
// Bpack: [4 kb][3 nt][64 lane][8] — Bblk[kcol (ffc colspace 0..107)][n (fb idx br*6+j)]
struct WkPtrs { const float* wk[12]; };

__global__ __launch_bounds__(256) void pack_conv(WkPtrs wp,
                                                 ushort_t* __restrict__ Apack,
                                                 ushort_t* __restrict__ Bpack) {
  int u = blockIdx.x * 256 + threadIdx.x;
  if (u < 20480) {
    int i = u & 7, lane = (u >> 3) & 63;
    int knt = u >> 9;                  // kb*5 + nt
    int kb = knt / 5, nt = knt % 5;
    int k = kb * 32 + ((lane >> 4) << 3) + i;
    int n = nt * 16 + (lane & 15);
    float val = 0.f;
    if (n < 72 && k < 240) {
      int br = n / 12, ii = n - br * 12, ks = br + 1, lin = 240 - br;
      int si = ii * lin / 12, ei = ((ii + 1) * lin + 11) / 12;
      const float* wa = wp.wk[2 * br];
      float acc = 0.f;
      for (int kk = 0; kk < ks; ++kk) {
        int j = k - kk;                 // conv position feeding pooled window
        if (j >= si && j < ei) acc += wa[kk];
      }
      val = acc / (float)(ei - si);
    }
    Apack[u] = f2bf(val);
  } else if (u < 20480 + 6144) {
    int v = u - 20480;
    int i = v & 7, lane = (v >> 3) & 63;
    int knt = v >> 9;                  // kb*3 + nt
    int kb = knt / 3, nt = knt % 3;
    int kcol = kb * 32 + ((lane >> 4) << 3) + i;
    int n = nt * 16 + (lane & 15);
    float val = 0.f;
    if (n < 36 && kcol < 108) {
      int brk = kcol / 18, ii = kcol - brk * 18;
      int brn = n / 6, j = n - brn * 6;
      if (brk == brn && ii < 12) {     // block-diagonal; fa positions only
        int ks = brn + 1, lcb = 12 - 2 * brn;
        int sj = j * lcb / 6, ej = ((j + 1) * lcb + 5) / 6;
        const float* wb = wp.wk[2 * brn + 1];
        float acc = 0.f;
        for (int kk = 0; kk < ks; ++kk) {
          int q = ii - 2 * kk;
          if (q >= sj && q < ej) acc += wb[kk];
        }
        val = acc / (float)(ej - sj);
      }
    }
    Bpack[v] = f2bf(val);
  }
}

// ---------------- Conv kernel: all-MFMA, 64 samples / block ------------------
struct ConvParams {
  const float* xw;
  const ushort_t* Apack;
  const ushort_t* Bpack;
  ushort_t*    ffc;        // packed B-frag order: ((kb*NSTILE + stile)*64 + lane)*8 + i
};

__global__ __launch_bounds__(512, 6) void conv_kernel(ConvParams p) {
  // LDS 48 KB -> 3 blocks/CU:
  //   [0,32768)      s_xw bf16[64][256] swz rb=512 (K pad 240->256)
  //   [32768,49152)  s_fc bf16[64][128] swz rb=256 (ffc colspace 0..107, pad 128)
  __shared__ __align__(16) char smem[49152];
  ushort_t* s_xw = (ushort_t*)smem;
  ushort_t* s_fc = (ushort_t*)(smem + 32768);

  const int t = threadIdx.x, lane = t & 63, w = t >> 6;
  const int s0 = blockIdx.x * 64;
  const f32x4 fzero = {0.f, 0.f, 0.f, 0.f};

  // zero s_fc fully (holes must be finite-zero for GEMM0b; pad for ffc out)
  for (int u = t; u < 1024; u += 512) ((uint4*)s_fc)[u] = uint4{0, 0, 0, 0};
  // zero xw pad cols 240..255
  if (t < 128) {
    int r = t >> 1, m = t & 1;
    *(uint4*)((char*)s_xw + ((r * 512 + 480 + m * 16) ^ ((r & 7) << 4))) = uint4{0, 0, 0, 0};
  }
  // stage xw f32 -> bf16 swizzled LDS
  for (int u = t; u < 64 * 60; u += 512) {
    int s = u / 60, m4 = u - s * 60;
    float4 v = *(const float4*)(p.xw + (size_t)(s0 + s) * 240 + 4 * m4);
    uint2 pkv; pkv.x = pk2(v.x, v.y); pkv.y = pk2(v.z, v.w);
    *(uint2*)((char*)s_xw + ((s * 512 + m4 * 8) ^ ((s & 7) << 4))) = pkv;
  }
  __syncthreads();

  // --- GEMM0a: FA[72 n][64 samp] = leaky(xw @ A); scatter to s_fc cols n+6*br
  auto do0a = [&](int nt, int st) {
    f32x4 acc = fzero;
    #pragma unroll
    for (int kb = 0; kb < 8; ++kb) {
      bf16x8 a = ld_frag(p.Apack + (size_t)((kb * 5 + nt) * 64 + lane) * 8);
      bf16x8 b = frag_swz(s_xw, st * 16 + (lane & 15), 512, kb * 32 + ((lane >> 4) << 3));
      acc = mfma16(a, b, acc);
    }
    int n0 = nt * 16 + ((lane >> 4) << 2);   // 4-aligned, within one branch (4|12)
    int br = n0 / 12;                        // br=6 for pad n>=72 -> col 108..115 (zero region, ok)
    int col0 = n0 + 6 * br;
    int row = st * 16 + (lane & 15);
    unsigned lo = pk2(lrelu(acc[0]), lrelu(acc[1]));
    unsigned hi = pk2(lrelu(acc[2]), lrelu(acc[3]));
    *(unsigned*)((char*)s_fc + ((row * 256 + col0 * 2) ^ ((row & 7) << 4))) = lo;
    *(unsigned*)((char*)s_fc + ((row * 256 + (col0 + 2) * 2) ^ ((row & 7) << 4))) = hi;
  };
  do0a(w % 5, w / 5);                 // 20 tiles over 8 waves
  do0a((w + 8) % 5, (w + 8) / 5);
  if (w < 4) do0a((w + 16) % 5, (w + 16) / 5);
  __syncthreads();

  // --- GEMM0b: FB[36 n][64 samp] = leaky(fa_colspace @ Bblk); accs first (race-free)
  const int nt0 = w % 3, st0 = w / 3;
  f32x4 accB0 = fzero, accB1 = fzero;
  #pragma unroll
  for (int kb = 0; kb < 4; ++kb) {
    bf16x8 a = ld_frag(p.Bpack + (size_t)((kb * 3 + nt0) * 64 + lane) * 8);
    bf16x8 b = frag_swz(s_fc, st0 * 16 + (lane & 15), 256, kb * 32 + ((lane >> 4) << 3));
    accB0 = mfma16(a, b, accB0);
  }
  const int nt1 = (w + 8) % 3, st1 = (w + 8) / 3;
  if (w < 4) {
    #pragma unroll
    for (int kb = 0; kb < 4; ++kb) {
      bf16x8 a = ld_frag(p.Bpack + (size_t)((kb * 3 + nt1) * 64 + lane) * 8);
      bf16x8 b = frag_swz(s_fc, st1 * 16 + (lane & 15), 256, kb * 32 + ((lane >> 4) << 3));
      accB1 = mfma16(a, b, accB1);
    }
  }
  __syncthreads();
  // fb epilogue: n = br*6+j -> col = n + 12*(br+1); per-pair (6 even => pair same br)
  auto wr0b = [&](f32x4 acc, int nt, int st) {
    int n0 = nt * 16 + ((lane >> 4) << 2);
    if (n0 < 36) {
      int row = st * 16 + (lane & 15);
      int br0 = n0 / 6, c0 = n0 + 12 * (br0 + 1);
      int n2 = n0 + 2, br2 = n2 / 6, c2 = n2 + 12 * (br2 + 1);
      *(unsigned*)((char*)s_fc + ((row * 256 + c0 * 2) ^ ((row & 7) << 4))) =
          pk2(lrelu(acc[0]), lrelu(acc[1]));
      *(unsigned*)((char*)s_fc + ((row * 256 + c2 * 2) ^ ((row & 7) << 4))) =
          pk2(lrelu(acc[2]), lrelu(acc[3]));
    }
  };
  wr0b(accB0, nt0, st0);
  if (w < 4) wr0b(accB1, nt1, st1);
  __syncthreads();

  // --- pack ffc to global in GEMM3 B-frag order (kb 0..3 = cols 0..127)
  for (int u = t; u < 1024; u += 512) {
    int ln = u & 63, st = (u >> 6) & 3, kb = u >> 8;
    int row = st * 16 + (ln & 15);
    int colb = (kb * 32 + ((ln >> 4) << 3)) * 2;
    uint4 v = *(const uint4*)((const char*)s_fc + ((row * 256 + colb) ^ ((row & 7) << 4)));
    size_t stile = (size_t)blockIdx.x * 4 + st;
    *(uint4*)((char*)p.ffc + (((size_t)kb * NSTILE + stile) * 64 + ln) * 16) = v;
  }
}

// ---------------- MLP kernel: 64 samples / block, 8 waves, 2 blocks/CU -------
struct MlpParams {
  const int*   xcat;
  const float* xcont;
  const float* E0; const float* E1; const float* E2;
  const float* b1; const float* b2;
  const ushort_t* w1p; const ushort_t* w2p; const ushort_t* wlp;
  const ushort_t* ffc;
  const float* stats;
  float*       out;
};

__global__ __launch_bounds__(512, 4) void mlp_kernel(MlpParams p) {
  // LDS: 73856 B -> 2 blocks/CU
  __shared__ __align__(16) char smem[73856];
  ushort_t* s_h1  = (ushort_t*)smem;              // [64][512] swz rb=1024
  ushort_t* s_fc  = (ushort_t*)smem;              // after GEMM2: [64][256] swz rb=512
  ushort_t* s_x48 = (ushort_t*)(smem + 65536);    // [64][64] swz rb=128
  float*    s_bn  = (float*)(smem + 73728);

  const int t    = threadIdx.x;
  const int lane = t & 63;
  const int w    = t >> 6;
  const int s0   = blockIdx.x * 64;
  const f32x4 fzero = {0.f, 0.f, 0.f, 0.f};

  if (t < 32) s_bn[t] = p.stats[t];
  for (int u = t; u < 64 * 16; u += 512) { int s = u >> 4; s_x48[swzi(s, 128, 48 + (u & 15))] = 0; }
  __syncthreads();

  for (int u = t; u < 64 * 48; u += 512) {
    int s = u / 48, c = u - s * 48, gs = s0 + s;
    float v;
    if (c < 20)      v = p.E0[(size_t)p.xcat[gs * 3 + 0] * 20 + c];
    else if (c < 24) v = p.E1[(size_t)p.xcat[gs * 3 + 1] * 4 + (c - 20)];
    else if (c < 32) v = p.E2[(size_t)p.xcat[gs * 3 + 2] * 8 + (c - 24)];
    else { int cc = c - 32; v = p.xcont[(size_t)gs * 16 + cc] * s_bn[cc] + s_bn[16 + cc]; }
    s_x48[swzi(s, 128, c)] = f2bf(v);
  }
  __syncthreads();

  // --- GEMM1: h1[n][samp] = relu(x48 @ W1 + b1); wave w: nt = 4w..4w+3
  {
    bf16x8 bx[4][2];
    #pragma unroll
    for (int st = 0; st < 4; ++st)
      #pragma unroll
      for (int kb = 0; kb < 2; ++kb)
        bx[st][kb] = frag_swz(s_x48, st * 16 + (lane & 15), 128, kb * 32 + ((lane >> 4) << 3));
    #pragma unroll
    for (int j = 0; j < 4; ++j) {
      int nt = w * 4 + j;
      bf16x8 a0 = ld_frag(p.w1p + (size_t)((0 * 32 + nt) * 64 + lane) * 8);
      bf16x8 a1 = ld_frag(p.w1p + (size_t)((1 * 32 + nt) * 64 + lane) * 8);
      f32x4 acc[4];
      #pragma unroll
      for (int st = 0; st < 4; ++st) {
        acc[st] = mfma16(a0, bx[st][0], fzero);
        acc[st] = mfma16(a1, bx[st][1], acc[st]);
      }
      int n0 = nt * 16 + ((lane >> 4) << 2);
      float4 bb = *(const float4*)(p.b1 + n0);
      #pragma unroll
      for (int st = 0; st < 4; ++st) {
        int row = st * 16 + (lane & 15);
        float v0 = fmaxf(acc[st][0] + bb.x, 0.f);
        float v1 = fmaxf(acc[st][1] + bb.y, 0.f);
        float v2 = fmaxf(acc[st][2] + bb.z, 0.f);
        float v3 = fmaxf(acc[st][3] + bb.w, 0.f);
        uint2 pkv; pkv.x = pk2(v0, v1); pkv.y = pk2(v2, v3);
        *(uint2*)((char*)s_h1 + ((row * 1024 + n0 * 2) ^ ((row & 7) << 4))) = pkv;
      }
    }
  }
  __syncthreads();

  // --- GEMM2: h2 = relu(h1 @ W2 + b2); wave w: nt = 2w, 2w+1; no K-loop barriers
  {
    const int nt0 = w * 2;
    f32x4 acc[2][4];
    #pragma unroll
    for (int jm = 0; jm < 2; ++jm)
      #pragma unroll
      for (int st = 0; st < 4; ++st) acc[jm][st] = fzero;
    uint4 pa[2][2];
    pa[0][0] = *(const uint4*)(p.w2p + (size_t)((0 * 16 + nt0 + 0) * 64 + lane) * 8);
    pa[0][1] = *(const uint4*)(p.w2p + (size_t)((0 * 16 + nt0 + 1) * 64 + lane) * 8);
    pa[1][0] = *(const uint4*)(p.w2p + (size_t)((1 * 16 + nt0 + 0) * 64 + lane) * 8);
    pa[1][1] = *(const uint4*)(p.w2p + (size_t)((1 * 16 + nt0 + 1) * 64 + lane) * 8);
    #pragma unroll
    for (int kb = 0; kb < 16; ++kb) {
      bf16x8 a0 = __builtin_bit_cast(bf16x8, pa[kb & 1][0]);
      bf16x8 a1 = __builtin_bit_cast(bf16x8, pa[kb & 1][1]);
      if (kb < 14) {
        pa[kb & 1][0] = *(const uint4*)(p.w2p + (size_t)(((kb + 2) * 16 + nt0 + 0) * 64 + lane) * 8);
        pa[kb & 1][1] = *(const uint4*)(p.w2p + (size_t)(((kb + 2) * 16 + nt0 + 1) * 64 + lane) * 8);
      }
      #pragma unroll
      for (int st = 0; st < 4; ++st) {
        bf16x8 b = frag_swz(s_h1, st * 16 + (lane & 15), 1024, kb * 32 + ((lane >> 4) << 3));
        acc[0][st] = mfma16(a0, b, acc[0][st]);
        acc[1][st] = mfma16(a1, b, acc[1][st]);
      }
    }
    __syncthreads();   // h1 reads complete before overlay with h2
    #pragma unroll
    for (int jm = 0; jm < 2; ++jm) {
      int n0 = (nt0 + jm) * 16 + ((lane >> 4) << 2);
      float4 bb = *(const float4*)(p.b2 + n0);
      #pragma unroll
      for (int st = 0; st < 4; ++st) {
        int row = st * 16 + (lane & 15);
        float v0 = fmaxf(acc[jm][st][0] + bb.x, 0.f);
        float v1 = fmaxf(acc[jm][st][1] + bb.y, 0.f);
        float v2 = fmaxf(acc[jm][st][2] + bb.z, 0.f);
        float v3 = fmaxf(acc[jm][st][3] + bb.w, 0.f);
        uint2 pkv; pkv.x = pk2(v0, v1); pkv.y = pk2(v2, v3);
        *(uint2*)((char*)s_fc + ((row * 512 + n0 * 2) ^ ((row & 7) << 4))) = pkv;
      }
    }
  }
  __syncthreads();

  // --- GEMM3: out[64][24] = [ffc(pad128) | h2] @ Wlin ; wave w: st = w&3, nt = w>>2
  {
    const int st = w & 3, nt = w >> 2;
    const size_t stile = (size_t)blockIdx.x * 4 + st;
    f32x4 acc = fzero;
    #pragma unroll
    for (int kb = 0; kb < 12; ++kb) {
      bf16x8 a = ld_frag(p.wlp + (size_t)((kb * 2 + nt) * 64 + lane) * 8);
      bf16x8 b;
      if (kb < 4) b = ld_frag(p.ffc + (((size_t)kb * NSTILE + stile) * 64 + lane) * 8);
      else        b = frag_swz(s_fc, st * 16 + (lane & 15), 512, (kb - 4) * 32 + ((lane >> 4) << 3));
      acc = mfma16(a, b, acc);
    }
    int n0 = nt * 16 + ((lane >> 4) << 2);
    if (n0 < 24) {
      int sg = s0 + st * 16 + (lane & 15);
      *(float2*)(p.out + (size_t)sg * 24 + n0)     = make_float2(acc[0], acc[1]);
      *(float2*)(p.out + (size_t)sg * 24 + n0 + 2) = make_float2(acc[2], acc[3]);
    }
  }
}

// ---------------- launch -----------------------------------------------------
extern "C" void kernel_launch(void* const* d_in, const int* in_sizes, int n_in,
                              void* d_out, int out_size, void* d_ws, size_t ws_size,
                              hipStream_t stream) {
  const float* xcont = (const float*)d_in[2];
  float* ws  = (float*)d_ws;
  char*  wsb = (char*)d_ws;
  ushort_t* w1p   = (ushort_t*)(wsb + 36864);    //  64 KB
  ushort_t* w2p   = (ushort_t*)(wsb + 102400);   // 256 KB
  ushort_t* wlp   = (ushort_t*)(wsb + 364544);   //  24 KB
  ushort_t* Apack = (ushort_t*)(wsb + 389120);   //  40 KB
  ushort_t* Bpack = (ushort_t*)(wsb + 430080);   //  12 KB
  ushort_t* ffc   = (ushort_t*)(wsb + 524288);   //  16.78 MB

  WkPtrs wp;
  for (int i = 0; i < 12; ++i) wp.wk[i] = (const float*)d_in[3 + i];
  pack_conv<<<104, 256, 0, stream>>>(wp, Apack, Bpack);

  ConvParams cp;
  cp.xw = (const float*)d_in[0];
  cp.Apack = Apack; cp.Bpack = Bpack;
  cp.ffc = ffc;
  conv_kernel<<<B_TOTAL / 64, 512, 0, stream>>>(cp);

  bn_partial<<<256, 256, 0, stream>>>(xcont, ws);
  bn_final<<<1, 256, 0, stream>>>(ws, ws, (const float*)d_in[18], (const float*)d_in[19]);
  pack_weights<<<688, 256, 0, stream>>>((const float*)d_in[20], (const float*)d_in[22],
                                        (const float*)d_in[24], w1p, w2p, wlp);

  MlpParams p;
  p.xcat  = (const int*)d_in[1];
  p.xcont = xcont;
  p.E0 = (const float*)d_in[15]; p.E1 = (const float*)d_in[16]; p.E2 = (const float*)d_in[17];
  p.b1 = (const float*)d_in[21]; p.b2 = (const float*)d_in[23];
  p.w1p = w1p; p.w2p = w2p; p.wlp = wlp; p.ffc = ffc;
  p.stats = ws + 8192;
  p.out = (float*)d_out;
  mlp_kernel<<<B_TOTAL / 64, 512, 0, stream>>>(p);
}